// Round 1
// baseline (257.244 us; speedup 1.0000x reference)
//
#include <hip/hip_runtime.h>
#include <math.h>

#define NTOK 32768          // B*L = 8*4096
#define DDIM 1024
#define HDIM 64
#define NB 16
#define LN_EPS 1e-5f

// ws float layout: [0:16) counts, [16:32) Psum, [32:96) csg, [96:160) csb

__global__ void colsum_kernel(const float* __restrict__ W1,
                              const float* __restrict__ gamma,
                              const float* __restrict__ beta,
                              float* ws) {
    __shared__ float sg[4][64];
    __shared__ float sb[4][64];
    const int t = threadIdx.x;          // 256
    const int j = t & 63;
    const int part = t >> 6;            // 0..3
    const int d0 = blockIdx.x * 64 + part * 16;
    float ag = 0.f, ab = 0.f;
    for (int dd = 0; dd < 16; ++dd) {
        const int d = d0 + dd;
        const float w = W1[d * HDIM + j];
        ag += gamma[d] * w;
        ab += beta[d] * w;
    }
    sg[part][j] = ag;
    sb[part][j] = ab;
    __syncthreads();
    if (t < 64) {
        atomicAdd(&ws[32 + t], sg[0][t] + sg[1][t] + sg[2][t] + sg[3][t]);
        atomicAdd(&ws[96 + t], sb[0][t] + sb[1][t] + sb[2][t] + sb[3][t]);
    }
}

__global__ __launch_bounds__(256, 2)
void router_main(const float* __restrict__ x,
                 const float* __restrict__ gamma,
                 const float* __restrict__ W1,
                 const float* __restrict__ W2,
                 float* ws,
                 float* __restrict__ out) {
    __shared__ __align__(16) float Asub[32][64];   // [k][m] transposed
    __shared__ __align__(16) float Bsub[32][64];   // [k][j]
    __shared__ __align__(16) float W2t[16][68];    // W2 transposed, padded
    __shared__ float csgl[64], csbl[64];
    __shared__ float s1l[64], s2l[64];
    __shared__ __align__(16) float ylds[64][64];
    __shared__ __align__(16) float plds[64][16];
    __shared__ __align__(16) float ilds[128];
    __shared__ __align__(16) float wlds[128];
    __shared__ float cntl[16];

    const int t = threadIdx.x;
    const int blk = blockIdx.x;
    const int tok0 = blk * 64;

    if (t < 64) {
        for (int i = 0; i < 16; ++i) W2t[i][t] = W2[t * NB + i];
        csgl[t] = ws[32 + t];
        csbl[t] = ws[96 + t];
    }
    if (t >= 64 && t < 80) cntl[t - 64] = 0.f;

    const int tx = t & 15, ty = t >> 4;
    const int m0 = ty * 4, j0 = tx * 4;
    float acc[4][4] = {};
    float s1a = 0.f, s2a = 0.f, s1b = 0.f, s2b = 0.f;

    const int arow = t >> 3;            // 0..31
    const int acol = (t & 7) * 4;       // 0,4,..28
    const int bkk  = t >> 4;            // 0..15
    const int bj   = (t & 15) * 4;      // 0..60

    for (int kc = 0; kc < 32; ++kc) {
        const int k0 = kc * 32;
        const float4 av0 = *(const float4*)&x[(size_t)(tok0 + arow) * DDIM + k0 + acol];
        const float4 av1 = *(const float4*)&x[(size_t)(tok0 + 32 + arow) * DDIM + k0 + acol];
        const float4 gv  = *(const float4*)&gamma[k0 + acol];
        const float4 bv0 = *(const float4*)&W1[(size_t)(k0 + bkk) * HDIM + bj];
        const float4 bv1 = *(const float4*)&W1[(size_t)(k0 + 16 + bkk) * HDIM + bj];
        __syncthreads();   // previous compute done before overwriting LDS

        s1a += av0.x + av0.y + av0.z + av0.w;
        s2a += av0.x * av0.x + av0.y * av0.y + av0.z * av0.z + av0.w * av0.w;
        s1b += av1.x + av1.y + av1.z + av1.w;
        s2b += av1.x * av1.x + av1.y * av1.y + av1.z * av1.z + av1.w * av1.w;

        Asub[acol + 0][arow] = av0.x * gv.x;
        Asub[acol + 1][arow] = av0.y * gv.y;
        Asub[acol + 2][arow] = av0.z * gv.z;
        Asub[acol + 3][arow] = av0.w * gv.w;
        Asub[acol + 0][32 + arow] = av1.x * gv.x;
        Asub[acol + 1][32 + arow] = av1.y * gv.y;
        Asub[acol + 2][32 + arow] = av1.z * gv.z;
        Asub[acol + 3][32 + arow] = av1.w * gv.w;
        *(float4*)&Bsub[bkk][bj] = bv0;
        *(float4*)&Bsub[16 + bkk][bj] = bv1;
        __syncthreads();

#pragma unroll
        for (int kk = 0; kk < 32; ++kk) {
            const float4 a = *(const float4*)&Asub[kk][m0];
            const float4 b = *(const float4*)&Bsub[kk][j0];
            const float aa[4] = {a.x, a.y, a.z, a.w};
            const float bb[4] = {b.x, b.y, b.z, b.w};
#pragma unroll
            for (int i = 0; i < 4; ++i)
#pragma unroll
                for (int j = 0; j < 4; ++j)
                    acc[i][j] += aa[i] * bb[j];
        }
    }

#pragma unroll
    for (int i = 0; i < 4; ++i) {
        float4 v;
        v.x = acc[i][0]; v.y = acc[i][1]; v.z = acc[i][2]; v.w = acc[i][3];
        *(float4*)&ylds[m0 + i][j0] = v;
    }
#pragma unroll
    for (int msk = 1; msk <= 4; msk <<= 1) {
        s1a += __shfl_xor(s1a, msk, 64);
        s2a += __shfl_xor(s2a, msk, 64);
        s1b += __shfl_xor(s1b, msk, 64);
        s2b += __shfl_xor(s2b, msk, 64);
    }
    if ((t & 7) == 0) {
        s1l[arow] = s1a; s2l[arow] = s2a;
        s1l[32 + arow] = s1b; s2l[32 + arow] = s2b;
    }
    __syncthreads();

    // GELU epilogue: thread (em, eq) handles token em, 16 cols
    const int em = t >> 2, eq = t & 3;
    const float mu = s1l[em] * (1.0f / 1024.0f);
    const float var = s2l[em] * (1.0f / 1024.0f) - mu * mu;
    const float rstd = 1.0f / sqrtf(var + LN_EPS);
#pragma unroll
    for (int jj = 0; jj < 16; ++jj) {
        const int j = eq * 16 + ((jj + em) & 15);   // bank-rotated
        const float y = ylds[em][j];
        const float pre = rstd * (y - mu * csgl[j]) + csbl[j];
        ylds[em][j] = 0.5f * pre * (1.0f + erff(pre * 0.70710678118654752f));
    }
    __syncthreads();

    float l[4] = {0.f, 0.f, 0.f, 0.f};
    for (int jj = 0; jj < 64; ++jj) {
        const int j = (jj + em) & 63;               // bank-rotated
        const float h = ylds[em][j];
#pragma unroll
        for (int c = 0; c < 4; ++c) l[c] += h * W2t[eq * 4 + c][j];
    }
#pragma unroll
    for (int c = 0; c < 4; ++c) plds[em][eq * 4 + c] = l[c] * 0.5f;  // /TEMP
    __syncthreads();

    if (t < 64) {
        float p[16];
        float mx = -1e30f;
#pragma unroll
        for (int i = 0; i < NB; ++i) { p[i] = plds[t][i]; mx = fmaxf(mx, p[i]); }
        float s = 0.f;
#pragma unroll
        for (int i = 0; i < NB; ++i) { p[i] = expf(p[i] - mx); s += p[i]; }
        const float inv = 1.0f / s;
#pragma unroll
        for (int i = 0; i < NB; ++i) { p[i] *= inv; plds[t][i] = p[i]; }
        float b0 = -1.f, b1 = -1.f;
        int i0 = 0, i1 = 0;
#pragma unroll
        for (int i = 0; i < NB; ++i) {
            if (p[i] > b0)      { b1 = b0; i1 = i0; b0 = p[i]; i0 = i; }
            else if (p[i] > b1) { b1 = p[i]; i1 = i; }
        }
        const float wsum = b0 + b1 + 1e-8f;
        ilds[t * 2] = (float)i0;
        ilds[t * 2 + 1] = (float)i1;
        wlds[t * 2] = b0 / wsum;
        wlds[t * 2 + 1] = b1 / wsum;
        atomicAdd(&cntl[i0], 1.0f);
        atomicAdd(&cntl[i1], 1.0f);
    }
    __syncthreads();

    *(float4*)&out[(size_t)tok0 * NB + t * 4] = *(const float4*)(&plds[0][0] + t * 4);
    if (t < 32)
        *(float4*)&out[(size_t)NTOK * NB + tok0 * 2 + t * 4] = *(const float4*)&ilds[t * 4];
    if (t < 128)
        out[(size_t)NTOK * NB + (size_t)NTOK * 2 + 1 + tok0 * 2 + t] = wlds[t];

    if (t < 16) {
        float ps = 0.f;
        for (int m = 0; m < 64; ++m) ps += plds[m][t];
        atomicAdd(&ws[16 + t], ps);     // Psum partial
        atomicAdd(&ws[t], cntl[t]);     // counts partial
    }
}

__global__ void aux_kernel(const float* ws, float* out) {
    if (threadIdx.x == 0) {
        float a = 0.f;
        for (int i = 0; i < NB; ++i) {
            const float f = ws[i] / (65536.0f + 1e-8f);        // B*L*K
            const float P = ws[16 + i] * (1.0f / 32768.0f);    // mean over B*L
            a += f * P;
        }
        out[(size_t)NTOK * NB + (size_t)NTOK * 2] = 16.0f * a; // NB * sum(f*P)
    }
}

extern "C" void kernel_launch(void* const* d_in, const int* in_sizes, int n_in,
                              void* d_out, int out_size, void* d_ws, size_t ws_size,
                              hipStream_t stream) {
    const float* x     = (const float*)d_in[0];
    const float* gamma = (const float*)d_in[1];
    const float* beta  = (const float*)d_in[2];
    const float* W1    = (const float*)d_in[3];
    const float* W2    = (const float*)d_in[4];
    float* out = (float*)d_out;
    float* ws  = (float*)d_ws;

    hipMemsetAsync(ws, 0, 160 * sizeof(float), stream);
    colsum_kernel<<<16, 256, 0, stream>>>(W1, gamma, beta, ws);
    router_main<<<NTOK / 64, 256, 0, stream>>>(x, gamma, W1, W2, ws, out);
    aux_kernel<<<1, 64, 0, stream>>>(ws, out);
}